// Round 14
// baseline (165.368 us; speedup 1.0000x reference)
//
#include <hip/hip_runtime.h>

typedef __bf16 bf16x8 __attribute__((ext_vector_type(8)));
typedef float  f32x4  __attribute__((ext_vector_type(4)));

__device__ __forceinline__ unsigned short f2bf(float f){
    union { float f; unsigned u; } v; v.f = f;
    v.u += 0x7fffu + ((v.u >> 16) & 1u);          // RNE
    return (unsigned short)(v.u >> 16);
}
// async 16B global->LDS. lptr wave-uniform; HW dest = lptr + lane*16.
__device__ __forceinline__ void gl2lds16(const unsigned short* g, unsigned short* l){
    __builtin_amdgcn_global_load_lds(
        (const __attribute__((address_space(1))) void*)g,
        (__attribute__((address_space(3))) void*)l, 16, 0, 0);
}

// ------- transpose+convert x,c AND weight convert, one launch -----------------
// Tile column-chunk XOR swizzle (col ^ ((row>>4&3)<<4)): removes the 8-way
// read bank conflict (2.6M conflict cycles measured R8).
__global__ __launch_bounds__(256) void transpose_cvt(const float* __restrict__ x, const float* __restrict__ c,
                                                     const float* __restrict__ w0, const float* __restrict__ w1,
                                                     const float* __restrict__ w2, const float* __restrict__ w3,
                                                     unsigned short* __restrict__ xt, unsigned short* __restrict__ ct,
                                                     unsigned short* __restrict__ o0, unsigned short* __restrict__ o1,
                                                     unsigned short* __restrict__ o2, unsigned short* __restrict__ o3){
    __shared__ float tile[64][72];
    const int z = blockIdx.z;
    if (z == 16){
        int fid = (blockIdx.x * 8 + blockIdx.y) * 256 + threadIdx.x;
        const float* in; unsigned short* out;
        switch (fid >> 13){
            case 0: in = w0; out = o0; break;
            case 1: in = w1; out = o1; break;
            case 2: in = w2; out = o2; break;
            default: in = w3; out = o3; break;
        }
        int off = (fid & 8191) * 32;
        #pragma unroll
        for (int j = 0; j < 8; j++){
            float4 v = *(const float4*)(in + off + j*4);
            ushort4 o; o.x = f2bf(v.x); o.y = f2bf(v.y); o.z = f2bf(v.z); o.w = f2bf(v.w);
            *(ushort4*)(out + off + j*4) = o;
        }
        return;
    }
    const float* in = (z < 8) ? x : c;
    unsigned short* out = (z < 8) ? xt : ct;
    const int b = z & 7;
    const int t0 = blockIdx.x * 64, c0 = blockIdx.y * 64;
    const int tid = threadIdx.x;
    {
        int r = tid >> 2, q = (tid & 3) * 16;
        int qs = q ^ (((r >> 4) & 3) << 4);        // swizzled column chunk
        const float* src = in + ((size_t)b * 512 + c0 + r) * 1024 + t0 + q;
        #pragma unroll
        for (int j = 0; j < 4; j++)
            *(float4*)&tile[r][qs + j*4] = ((const float4*)src)[j];
    }
    __syncthreads();
    {
        int tr = tid >> 2, cj = (tid & 3) * 16;
        const int fsw = ((cj >> 4) & 3) << 4;      // same XOR key: rows cj..cj+15
        unsigned pw[8];
        #pragma unroll
        for (int j = 0; j < 8; j++){
            unsigned lo = f2bf(tile[cj + 2*j    ][tr ^ fsw]);
            unsigned hi = f2bf(tile[cj + 2*j + 1][tr ^ fsw]);
            pw[j] = lo | (hi << 16);
        }
        unsigned short* dst = out + ((size_t)b * 1024 + t0 + tr) * 512 + c0 + cj;
        uint4 q0 = {pw[0], pw[1], pw[2], pw[3]};
        uint4 q1 = {pw[4], pw[5], pw[6], pw[7]};
        ((uint4*)dst)[0] = q0;
        ((uint4*)dst)[1] = q1;
    }
}

// ---------------- merged QKV GEMM: BK=32, dbuf LDS = 32 KB --------------------
// R13 counters: MfmaUtil=VALUBusy=9.9%, Occ 16% at 64 KB dbuf (2 blocks/CU,
// grid 768 -> forced tail round). BK 64->32 halves LDS to 32 KB -> all 768
// blocks co-resident (3/CU, 12 waves/CU), zero tail, dbuf overlap kept.
// Same K-accumulation order -> bit-identical results. Chunk swizzle re-derived
// for 4-chunk (64 B) rows: stage source chunk c4^(r16&3); fragment read at
// (l4^(l15&3)) recovers chunk l4 of each row (A[row=l15][k=l4*8+j], same as BK=64).
__global__ __launch_bounds__(256) void qkv_gemm(const unsigned short* __restrict__ xt,
                                                const unsigned short* __restrict__ ct,
                                                const unsigned short* __restrict__ wq,
                                                const unsigned short* __restrict__ wk,
                                                const unsigned short* __restrict__ wv,
                                                const float* __restrict__ bq_,
                                                const float* __restrict__ bk_,
                                                const float* __restrict__ bv_,
                                                unsigned short* __restrict__ qt,
                                                unsigned short* __restrict__ kt,
                                                unsigned short* __restrict__ vct){
    __shared__ unsigned short a_s[2*128*32];       // 16 KB
    __shared__ unsigned short b_s[2*128*32];       // 16 KB
    const int z = blockIdx.y;
    const int xr = blockIdx.x;
    const int bid = (xr & 7) * 32 + (xr >> 3);     // chunked XCD swizzle (bijective)
    const unsigned short *A, *Bm;
    int m0, n0;
    if (z == 0){ A = xt; Bm = wq; m0 = (bid >> 2)*128; n0 = (bid & 3)*128; }
    else if (z == 1){ A = ct; Bm = wk; m0 = (bid >> 2)*128; n0 = (bid & 3)*128; }
    else { A = wv; Bm = ct; m0 = (bid & 3)*128; n0 = (bid >> 2)*128; }
    const int tid = threadIdx.x;
    const int wave = tid >> 6, lane = tid & 63;
    const int l15 = lane & 15, l4 = lane >> 4;
    const int mw = (wave >> 1) * 64, nw = (wave & 1) * 64;
    const int r16 = lane >> 2, c4 = lane & 3;      // 16-row group staging coords
    const int csw = (c4 ^ (r16 & 3)) * 8;          // swizzled source chunk (shorts)
    const int rp = l15 & 3;                        // read-side XOR key
    const f32x4 vzero = {0.f, 0.f, 0.f, 0.f};
    f32x4 acc[4][4];
    #pragma unroll
    for (int i = 0; i < 4; i++)
        #pragma unroll
        for (int j = 0; j < 4; j++) acc[i][j] = vzero;

    auto stage = [&](int k0, int buf){
        unsigned short* as = a_s + buf * (128*32);
        unsigned short* bs = b_s + buf * (128*32);
        #pragma unroll
        for (int i = 0; i < 2; i++){
            int rg = i * 4 + wave;                 // 0..7 -> 16-row group
            int row = rg * 16 + r16;
            gl2lds16(A  + (size_t)(m0 + row) * 512 + k0 + csw, as + rg * 512);
            gl2lds16(Bm + (size_t)(n0 + row) * 512 + k0 + csw, bs + rg * 512);
        }
    };

    stage(0, 0);
    __syncthreads();

    for (int t = 0; t < 16; t++){
        const int buf = t & 1;
        if (t < 15) stage((t + 1) * 32, buf ^ 1);  // next tile in flight over compute
        const unsigned short* as = a_s + buf * (128*32);
        const unsigned short* bs = b_s + buf * (128*32);
        bf16x8 af[4], bfr[4];
        #pragma unroll
        for (int mt = 0; mt < 4; mt++)
            af[mt] = *(const bf16x8*)&as[(mw + mt*16 + l15)*32 + ((l4 ^ rp) * 8)];
        #pragma unroll
        for (int ct = 0; ct < 4; ct++)
            bfr[ct] = *(const bf16x8*)&bs[(nw + ct*16 + l15)*32 + ((l4 ^ rp) * 8)];
        #pragma unroll
        for (int mt = 0; mt < 4; mt++)
            #pragma unroll
            for (int ct = 0; ct < 4; ct++)
                acc[mt][ct] = __builtin_amdgcn_mfma_f32_16x16x32_bf16(
                    af[mt], bfr[ct], acc[mt][ct], 0, 0, 0);
        __syncthreads();                           // drains stage(t+1) + WAR order
    }

    if (z < 2){
        unsigned short* out = (z == 0) ? qt : kt;
        const float* bias = (z == 0) ? bq_ : bk_;
        // q pre-scaled by (1/8)*log2(e) so flash uses exp2 directly
        const float osc = (z == 0) ? 0.1803368801111137f : 1.0f;
        float bv4[4];
        #pragma unroll
        for (int ct2 = 0; ct2 < 4; ct2++) bv4[ct2] = bias[n0 + nw + ct2*16 + l15];
        const float theta = __powf(10000.0f, -(float)l15 * (1.0f / 16.0f));
        #pragma unroll
        for (int mt = 0; mt < 4; mt++){
            #pragma unroll
            for (int rr = 0; rr < 4; rr++){
                int row = m0 + mw + mt*16 + l4*4 + rr;     // flat b*1024+t
                int t = row & 1023;
                float v[4];
                #pragma unroll
                for (int ct2 = 0; ct2 < 4; ct2++) v[ct2] = acc[mt][ct2][rr] + bv4[ct2];
                float sn, cn;
                __sincosf((float)t * theta, &sn, &cn);
                float r0 = v[0] * cn - v[1] * sn;
                float r1 = v[1] * cn + v[0] * sn;
                v[0] = r0; v[1] = r1;
                #pragma unroll
                for (int ct2 = 0; ct2 < 4; ct2++)
                    out[(size_t)row * 512 + n0 + nw + ct2*16 + l15] = f2bf(v[ct2] * osc);
            }
        }
    } else {
        #pragma unroll
        for (int mt = 0; mt < 4; mt++){
            #pragma unroll
            for (int rr = 0; rr < 4; rr++){
                int row = m0 + mw + mt*16 + l4*4 + rr;     // o index
                float bb = bv_[row];
                #pragma unroll
                for (int ct2 = 0; ct2 < 4; ct2++){
                    int n = n0 + nw + ct2*16 + l15;        // flat b*1024+t
                    size_t oaddr = (size_t)(n >> 10) * 524288 + (size_t)row * 1024 + (n & 1023);
                    vct[oaddr] = f2bf(acc[mt][ct2][rr] + bb);
                }
            }
        }
    }
}

// ---------------- final GEMM (2-phase dbuf): out = Wo*attnT^T + bo, f32 -------
// 64x128 tile, grid 8x64 = 512 blocks. (unchanged, ~10us)
__global__ __launch_bounds__(256) void gemm_o(const unsigned short* __restrict__ wo,
                                              const unsigned short* __restrict__ attnT,
                                              const float* __restrict__ bo,
                                              float* __restrict__ out){
    __shared__ unsigned short a_s[2*64*64];
    __shared__ unsigned short b_s[2*128*64];
    const int m0 = blockIdx.x * 64, n0 = blockIdx.y * 128;
    const int tid = threadIdx.x;
    const int wave = tid >> 6, lane = tid & 63;
    const int l15 = lane & 15, l4 = lane >> 4;
    const int nw = wave * 32;
    const int r8 = lane >> 3, c8l = lane & 7;
    const int csw = (c8l ^ r8) * 8;
    const int rp = l15 & 7;
    const f32x4 vzero = {0.f, 0.f, 0.f, 0.f};
    f32x4 acc[4][2];
    #pragma unroll
    for (int i = 0; i < 4; i++){ acc[i][0] = vzero; acc[i][1] = vzero; }

    auto stage = [&](int k0, int buf){
        unsigned short* as = a_s + buf * (64*64);
        unsigned short* bs = b_s + buf * (128*64);
        #pragma unroll
        for (int i = 0; i < 2; i++){               // A: 64 rows = 8 groups
            int rg = wave * 2 + i;
            gl2lds16(wo + (size_t)(m0 + rg*8 + r8) * 512 + k0 + csw, as + rg * 512);
        }
        #pragma unroll
        for (int i = 0; i < 4; i++){               // B: 128 rows = 16 groups
            int rg = wave * 4 + i;
            gl2lds16(attnT + (size_t)(n0 + rg*8 + r8) * 512 + k0 + csw, bs + rg * 512);
        }
    };

    stage(0, 0);
    __syncthreads();

    for (int t = 0; t < 8; t++){
        const int buf = t & 1;
        if (t < 7) stage((t + 1) * 64, buf ^ 1);
        const unsigned short* as = a_s + buf * (64*64);
        const unsigned short* bs = b_s + buf * (128*64);
        #pragma unroll
        for (int kk = 0; kk < 2; kk++){
            bf16x8 af[4], bfr[2];
            #pragma unroll
            for (int mt = 0; mt < 4; mt++)
                af[mt] = *(const bf16x8*)&as[(mt*16 + l15)*64 + (((kk*4) + l4) ^ rp)*8];
            #pragma unroll
            for (int ct = 0; ct < 2; ct++)
                bfr[ct] = *(const bf16x8*)&bs[(nw + ct*16 + l15)*64 + (((kk*4) + l4) ^ rp)*8];
            #pragma unroll
            for (int mt = 0; mt < 4; mt++)
                #pragma unroll
                for (int ct = 0; ct < 2; ct++)
                    acc[mt][ct] = __builtin_amdgcn_mfma_f32_16x16x32_bf16(
                        af[mt], bfr[ct], acc[mt][ct], 0, 0, 0);
        }
        __syncthreads();
    }

    #pragma unroll
    for (int mt = 0; mt < 4; mt++){
        #pragma unroll
        for (int rr = 0; rr < 4; rr++){
            int row = m0 + mt*16 + l4*4 + rr;              // o index
            float bb = bo[row];
            #pragma unroll
            for (int ct2 = 0; ct2 < 2; ct2++){
                int n = n0 + nw + ct2*16 + l15;            // flat b*1024+t
                size_t oaddr = (size_t)(n >> 10) * 524288 + (size_t)row * 1024 + (n & 1023);
                out[oaddr] = acc[mt][ct2][rr] + bb;
            }
        }
    }
}

// ---------------- flash attention: R13-verified (exp2 intrinsic) --------------
__global__ __launch_bounds__(256, 2) void flash_attn(const unsigned short* __restrict__ qt,
                                                     const unsigned short* __restrict__ kt,
                                                     const unsigned short* __restrict__ vct,
                                                     unsigned short* __restrict__ attnT){
    __shared__ unsigned short k_s[3][64*64];
    __shared__ unsigned short v_s[3][64*64];
    const int bhq = blockIdx.x;
    const int bh = bhq & 63, b = bh >> 3, h = bh & 7;
    const int q0 = (bhq >> 6) * 128;
    const int tid = threadIdx.x, wave = tid >> 6, lane = tid & 63;
    const int l15 = lane & 15, l4 = lane >> 4;
    const int r8 = lane >> 3, c8l = lane & 7;
    const int csw = (c8l ^ r8) * 8;
    const int rp = l15 & 7;
    const f32x4 vzero = {0.f, 0.f, 0.f, 0.f};
    const unsigned short* kbase = kt  + (size_t)(b*1024)*512 + h*64;
    const unsigned short* vbase = vct + (size_t)(b*512 + h*64)*1024;

    bf16x8 qf[2][2];
    #pragma unroll
    for (int st = 0; st < 2; st++)
        #pragma unroll
        for (int kh = 0; kh < 2; kh++)
            qf[st][kh] = *(const bf16x8*)(qt + (size_t)(b*1024 + q0 + wave*32 + st*16 + l15)*512
                                             + h*64 + kh*32 + l4*8);
    f32x4 o_acc[2][4], l_acc[2];
    #pragma unroll
    for (int st = 0; st < 2; st++){
        l_acc[st] = vzero;
        #pragma unroll
        for (int dt = 0; dt < 4; dt++) o_acc[st][dt] = vzero;
    }
    const __bf16 one_bf = (__bf16)1.0f;
    const bf16x8 ones = {one_bf, one_bf, one_bf, one_bf, one_bf, one_bf, one_bf, one_bf};

    auto stage = [&](int tile, int buf){
        const int s0n = tile * 64;
        #pragma unroll
        for (int i = 0; i < 2; i++){
            int rg = i * 4 + wave;
            int row = rg * 8 + r8;
            gl2lds16(kbase + (size_t)(s0n + row)*512 + csw, &k_s[buf][rg*512]);
            gl2lds16(vbase + (size_t)row*1024 + s0n + csw, &v_s[buf][rg*512]);
        }
    };
    stage(0, 0);
    stage(1, 1);

    const int voff0 = (l4 & 1) * 4;                // within-chunk half (shorts)
    for (int it = 0; it < 16; ++it){
        const int cur = it % 3;
        // own stage(it) landed; stage(it+1)'s 4 loads stay in flight
        if (it == 15) asm volatile("s_waitcnt vmcnt(0)" ::: "memory");
        else          asm volatile("s_waitcnt vmcnt(4)" ::: "memory");
        __builtin_amdgcn_s_barrier();              // all waves' stage(it) landed
        if (it < 14) stage(it + 2, (it + 2) % 3);  // writes buf[(it-1)%3]: reads done

        bf16x8 kf[2][4];
        #pragma unroll
        for (int kh = 0; kh < 2; kh++)
            #pragma unroll
            for (int ct = 0; ct < 4; ct++)
                kf[kh][ct] = *(const bf16x8*)&k_s[cur][(ct*16 + l15)*64 + ((kh*4 + l4) ^ rp)*8];
        union bfv { bf16x8 v; uint2 u[2]; };
        bfv vfp[2][4];
        #pragma unroll
        for (int c2 = 0; c2 < 2; c2++)
            #pragma unroll
            for (int dt = 0; dt < 4; dt++){
                const int base = (dt*16 + l15)*64;
                const int ch0 = ((c2*4 +     (l4 >> 1)) ^ rp)*8 + voff0;
                const int ch1 = ((c2*4 + 2 + (l4 >> 1)) ^ rp)*8 + voff0;
                vfp[c2][dt].u[0] = *(const uint2*)&v_s[cur][base + ch0];
                vfp[c2][dt].u[1] = *(const uint2*)&v_s[cur][base + ch1];
            }
        #pragma unroll
        for (int st = 0; st < 2; st++){
            f32x4 sa[4];
            #pragma unroll
            for (int ct = 0; ct < 4; ct++) sa[ct] = vzero;
            // swapped operands: S^T -> lane holds S[k=ct*16+l4*4+rr][q=l15]
            #pragma unroll
            for (int kh = 0; kh < 2; kh++)
                #pragma unroll
                for (int ct = 0; ct < 4; ct++)
                    sa[ct] = __builtin_amdgcn_mfma_f32_16x16x32_bf16(kf[kh][ct], qf[st][kh], sa[ct], 0, 0, 0);
            // raw v_exp_f32 via compiler-visible intrinsic (hazards handled)
            #pragma unroll
            for (int ct = 0; ct < 4; ct++)
                #pragma unroll
                for (int rr = 0; rr < 4; rr++)
                    sa[ct][rr] = __builtin_amdgcn_exp2f(sa[ct][rr]);   // q carries log2e/8
            // pack P into A-fragments entirely in-register (trunc, as baseline)
            bf16x8 ap[2];
            #pragma unroll
            for (int c2 = 0; c2 < 2; c2++){
                union { unsigned u[4]; bf16x8 v; } pw;
                #pragma unroll
                for (int c1 = 0; c1 < 2; c1++){
                    union { float f; unsigned u; } x0, x1, x2, x3;
                    x0.f = sa[2*c2+c1][0]; x1.f = sa[2*c2+c1][1];
                    x2.f = sa[2*c2+c1][2]; x3.f = sa[2*c2+c1][3];
                    pw.u[c1*2+0] = (x0.u >> 16) | (x1.u & 0xffff0000u);
                    pw.u[c1*2+1] = (x2.u >> 16) | (x3.u & 0xffff0000u);
                }
                ap[c2] = pw.v;
            }
            l_acc[st] = __builtin_amdgcn_mfma_f32_16x16x32_bf16(ap[0], ones, l_acc[st], 0, 0, 0);
            l_acc[st] = __builtin_amdgcn_mfma_f32_16x16x32_bf16(ap[1], ones, l_acc[st], 0, 0, 0);
            #pragma unroll
            for (int dt = 0; dt < 4; dt++){
                o_acc[st][dt] = __builtin_amdgcn_mfma_f32_16x16x32_bf16(ap[0], vfp[0][dt].v, o_acc[st][dt], 0, 0, 0);
                o_acc[st][dt] = __builtin_amdgcn_mfma_f32_16x16x32_bf16(ap[1], vfp[1][dt].v, o_acc[st][dt], 0, 0, 0);
            }
        }
    }
    #pragma unroll
    for (int st = 0; st < 2; st++){
        float rl[4];
        #pragma unroll
        for (int rr = 0; rr < 4; rr++) rl[rr] = __builtin_amdgcn_rcpf(l_acc[st][rr]);
        #pragma unroll
        for (int dt = 0; dt < 4; dt++)
            #pragma unroll
            for (int rr = 0; rr < 4; rr++){
                int row = q0 + wave*32 + st*16 + l4*4 + rr;
                attnT[(size_t)(b*1024 + row)*512 + h*64 + dt*16 + l15] = f2bf(o_acc[st][dt][rr] * rl[rr]);
            }
    }
}

extern "C" void kernel_launch(void* const* d_in, const int* in_sizes, int n_in,
                              void* d_out, int out_size, void* d_ws, size_t ws_size,
                              hipStream_t stream){
    const float* x  = (const float*)d_in[0];
    const float* c  = (const float*)d_in[1];
    const float* Wq = (const float*)d_in[2];
    const float* bq = (const float*)d_in[3];
    const float* Wk = (const float*)d_in[4];
    const float* bk = (const float*)d_in[5];
    const float* Wv = (const float*)d_in[6];
    const float* bv = (const float*)d_in[7];
    const float* Wo = (const float*)d_in[8];
    const float* bo = (const float*)d_in[9];

    unsigned short* wq_b = (unsigned short*)d_ws;
    unsigned short* wk_b = wq_b + 262144;
    unsigned short* wv_b = wk_b + 262144;
    unsigned short* wo_b = wv_b + 262144;
    unsigned short* xt   = wo_b + 262144;
    unsigned short* ct   = xt  + 4194304;
    unsigned short* qt   = ct  + 4194304;
    unsigned short* kt   = qt  + 4194304;
    unsigned short* vct  = kt  + 4194304;
    unsigned short* attnT = xt;                            // xt dead after q-GEMM

    transpose_cvt<<<dim3(16, 8, 17), 256, 0, stream>>>(x, c, Wq, Wk, Wv, Wo,
                                                       xt, ct, wq_b, wk_b, wv_b, wo_b);
    qkv_gemm<<<dim3(256, 3), 256, 0, stream>>>(xt, ct, wq_b, wk_b, wv_b, bq, bk, bv, qt, kt, vct);
    flash_attn<<<dim3(512), 256, 0, stream>>>(qt, kt, vct, attnT);
    gemm_o<<<dim3(8, 64), 256, 0, stream>>>(wo_b, attnT, bo, (float*)d_out);
}

// Round 15
// 159.392 us; speedup vs baseline: 1.0375x; 1.0375x over previous
//
#include <hip/hip_runtime.h>

typedef __bf16 bf16x8 __attribute__((ext_vector_type(8)));
typedef float  f32x4  __attribute__((ext_vector_type(4)));

__device__ __forceinline__ unsigned short f2bf(float f){
    union { float f; unsigned u; } v; v.f = f;
    v.u += 0x7fffu + ((v.u >> 16) & 1u);          // RNE
    return (unsigned short)(v.u >> 16);
}
// async 16B global->LDS. lptr wave-uniform; HW dest = lptr + lane*16.
__device__ __forceinline__ void gl2lds16(const unsigned short* g, unsigned short* l){
    __builtin_amdgcn_global_load_lds(
        (const __attribute__((address_space(1))) void*)g,
        (__attribute__((address_space(3))) void*)l, 16, 0, 0);
}

// ------- transpose+convert x,c AND weight convert, one launch -----------------
// Tile column-chunk XOR swizzle (col ^ ((row>>4&3)<<4)): removes the 8-way
// read bank conflict (2.6M conflict cycles measured R8).
__global__ __launch_bounds__(256) void transpose_cvt(const float* __restrict__ x, const float* __restrict__ c,
                                                     const float* __restrict__ w0, const float* __restrict__ w1,
                                                     const float* __restrict__ w2, const float* __restrict__ w3,
                                                     unsigned short* __restrict__ xt, unsigned short* __restrict__ ct,
                                                     unsigned short* __restrict__ o0, unsigned short* __restrict__ o1,
                                                     unsigned short* __restrict__ o2, unsigned short* __restrict__ o3){
    __shared__ float tile[64][72];
    const int z = blockIdx.z;
    if (z == 16){
        int fid = (blockIdx.x * 8 + blockIdx.y) * 256 + threadIdx.x;
        const float* in; unsigned short* out;
        switch (fid >> 13){
            case 0: in = w0; out = o0; break;
            case 1: in = w1; out = o1; break;
            case 2: in = w2; out = o2; break;
            default: in = w3; out = o3; break;
        }
        int off = (fid & 8191) * 32;
        #pragma unroll
        for (int j = 0; j < 8; j++){
            float4 v = *(const float4*)(in + off + j*4);
            ushort4 o; o.x = f2bf(v.x); o.y = f2bf(v.y); o.z = f2bf(v.z); o.w = f2bf(v.w);
            *(ushort4*)(out + off + j*4) = o;
        }
        return;
    }
    const float* in = (z < 8) ? x : c;
    unsigned short* out = (z < 8) ? xt : ct;
    const int b = z & 7;
    const int t0 = blockIdx.x * 64, c0 = blockIdx.y * 64;
    const int tid = threadIdx.x;
    {
        int r = tid >> 2, q = (tid & 3) * 16;
        int qs = q ^ (((r >> 4) & 3) << 4);        // swizzled column chunk
        const float* src = in + ((size_t)b * 512 + c0 + r) * 1024 + t0 + q;
        #pragma unroll
        for (int j = 0; j < 4; j++)
            *(float4*)&tile[r][qs + j*4] = ((const float4*)src)[j];
    }
    __syncthreads();
    {
        int tr = tid >> 2, cj = (tid & 3) * 16;
        const int fsw = ((cj >> 4) & 3) << 4;      // same XOR key: rows cj..cj+15
        unsigned pw[8];
        #pragma unroll
        for (int j = 0; j < 8; j++){
            unsigned lo = f2bf(tile[cj + 2*j    ][tr ^ fsw]);
            unsigned hi = f2bf(tile[cj + 2*j + 1][tr ^ fsw]);
            pw[j] = lo | (hi << 16);
        }
        unsigned short* dst = out + ((size_t)b * 1024 + t0 + tr) * 512 + c0 + cj;
        uint4 q0 = {pw[0], pw[1], pw[2], pw[3]};
        uint4 q1 = {pw[4], pw[5], pw[6], pw[7]};
        ((uint4*)dst)[0] = q0;
        ((uint4*)dst)[1] = q1;
    }
}

// ============ 2-phase GEMM mainloop: 128x128 tile, K=512, dbuf LDS ============
// XOR-chunk swizzle: chunk c of row stored at position c^(row&7).
__device__ __forceinline__ void gemm_mainloop(const unsigned short* __restrict__ A,
                                              const unsigned short* __restrict__ Bm,
                                              unsigned short* a_s, unsigned short* b_s,
                                              int m0, int n0, int tid, f32x4 acc[4][4]){
    const int wave = tid >> 6, lane = tid & 63;
    const int l15 = lane & 15, l4 = lane >> 4;
    const int mw = (wave >> 1) * 64, nw = (wave & 1) * 64;
    const int r8 = lane >> 3, c8l = lane & 7;
    const int csw = (c8l ^ r8) * 8;                // swizzled source chunk (shorts)
    const int rp = l15 & 7;

    auto stage = [&](int k0, int buf){
        unsigned short* as = a_s + buf * (128*64);
        unsigned short* bs = b_s + buf * (128*64);
        #pragma unroll
        for (int i = 0; i < 4; i++){
            int rg = i * 4 + wave;                 // 0..15 -> 8-row group
            int row = rg * 8 + r8;
            gl2lds16(A  + (size_t)(m0 + row) * 512 + k0 + csw, as + rg * 512);
            gl2lds16(Bm + (size_t)(n0 + row) * 512 + k0 + csw, bs + rg * 512);
        }
    };

    stage(0, 0);
    __syncthreads();

    for (int t = 0; t < 8; t++){
        const int buf = t & 1;
        if (t < 7) stage((t + 1) * 64, buf ^ 1);   // next tile in flight over compute
        const unsigned short* as = a_s + buf * (128*64);
        const unsigned short* bs = b_s + buf * (128*64);
        #pragma unroll
        for (int kk = 0; kk < 2; kk++){
            bf16x8 af[4], bfr[4];
            #pragma unroll
            for (int mt = 0; mt < 4; mt++)
                af[mt] = *(const bf16x8*)&as[(mw + mt*16 + l15)*64 + (((kk*4) + l4) ^ rp)*8];
            #pragma unroll
            for (int ct = 0; ct < 4; ct++)
                bfr[ct] = *(const bf16x8*)&bs[(nw + ct*16 + l15)*64 + (((kk*4) + l4) ^ rp)*8];
            #pragma unroll
            for (int mt = 0; mt < 4; mt++)
                #pragma unroll
                for (int ct = 0; ct < 4; ct++)
                    acc[mt][ct] = __builtin_amdgcn_mfma_f32_16x16x32_bf16(
                        af[mt], bfr[ct], acc[mt][ct], 0, 0, 0);
        }
        __syncthreads();                           // drains stage(t+1) + WAR order
    }
}

// ---------------- merged QKV GEMM: blockIdx.y = z (0:q,1:k,2:v) ---------------
__global__ __launch_bounds__(256) void qkv_gemm(const unsigned short* __restrict__ xt,
                                                const unsigned short* __restrict__ ct,
                                                const unsigned short* __restrict__ wq,
                                                const unsigned short* __restrict__ wk,
                                                const unsigned short* __restrict__ wv,
                                                const float* __restrict__ bq_,
                                                const float* __restrict__ bk_,
                                                const float* __restrict__ bv_,
                                                unsigned short* __restrict__ qt,
                                                unsigned short* __restrict__ kt,
                                                unsigned short* __restrict__ vct){
    __shared__ unsigned short a_s[2*128*64];
    __shared__ unsigned short b_s[2*128*64];
    const int z = blockIdx.y;
    const int xr = blockIdx.x;
    const int bid = (xr & 7) * 32 + (xr >> 3);     // chunked XCD swizzle (bijective)
    const unsigned short *A, *Bm;
    int m0, n0;
    if (z == 0){ A = xt; Bm = wq; m0 = (bid >> 2)*128; n0 = (bid & 3)*128; }
    else if (z == 1){ A = ct; Bm = wk; m0 = (bid >> 2)*128; n0 = (bid & 3)*128; }
    else { A = wv; Bm = ct; m0 = (bid & 3)*128; n0 = (bid >> 2)*128; }
    const int tid = threadIdx.x;
    const int wave = tid >> 6, lane = tid & 63;
    const int l15 = lane & 15, l4 = lane >> 4;
    const int mw = (wave >> 1) * 64, nw = (wave & 1) * 64;
    const f32x4 vzero = {0.f, 0.f, 0.f, 0.f};
    f32x4 acc[4][4];
    #pragma unroll
    for (int i = 0; i < 4; i++)
        #pragma unroll
        for (int j = 0; j < 4; j++) acc[i][j] = vzero;

    gemm_mainloop(A, Bm, a_s, b_s, m0, n0, tid, acc);

    if (z < 2){
        unsigned short* out = (z == 0) ? qt : kt;
        const float* bias = (z == 0) ? bq_ : bk_;
        // q pre-scaled by (1/8)*log2(e) so flash uses exp2 directly
        const float osc = (z == 0) ? 0.1803368801111137f : 1.0f;
        float bv4[4];
        #pragma unroll
        for (int ct2 = 0; ct2 < 4; ct2++) bv4[ct2] = bias[n0 + nw + ct2*16 + l15];
        const float theta = __powf(10000.0f, -(float)l15 * (1.0f / 16.0f));
        #pragma unroll
        for (int mt = 0; mt < 4; mt++){
            #pragma unroll
            for (int rr = 0; rr < 4; rr++){
                int row = m0 + mw + mt*16 + l4*4 + rr;     // flat b*1024+t
                int t = row & 1023;
                float v[4];
                #pragma unroll
                for (int ct2 = 0; ct2 < 4; ct2++) v[ct2] = acc[mt][ct2][rr] + bv4[ct2];
                float sn, cn;
                __sincosf((float)t * theta, &sn, &cn);
                float r0 = v[0] * cn - v[1] * sn;
                float r1 = v[1] * cn + v[0] * sn;
                v[0] = r0; v[1] = r1;
                #pragma unroll
                for (int ct2 = 0; ct2 < 4; ct2++)
                    out[(size_t)row * 512 + n0 + nw + ct2*16 + l15] = f2bf(v[ct2] * osc);
            }
        }
    } else {
        #pragma unroll
        for (int mt = 0; mt < 4; mt++){
            #pragma unroll
            for (int rr = 0; rr < 4; rr++){
                int row = m0 + mw + mt*16 + l4*4 + rr;     // o index
                float bb = bv_[row];
                #pragma unroll
                for (int ct2 = 0; ct2 < 4; ct2++){
                    int n = n0 + nw + ct2*16 + l15;        // flat b*1024+t
                    size_t oaddr = (size_t)(n >> 10) * 524288 + (size_t)row * 1024 + (n & 1023);
                    vct[oaddr] = f2bf(acc[mt][ct2][rr] + bb);
                }
            }
        }
    }
}

// ---------------- final GEMM (2-phase dbuf): out = Wo*attnT^T + bo, f32 -------
// 64x128 tile, grid 8x64 = 512 blocks.
__global__ __launch_bounds__(256) void gemm_o(const unsigned short* __restrict__ wo,
                                              const unsigned short* __restrict__ attnT,
                                              const float* __restrict__ bo,
                                              float* __restrict__ out){
    __shared__ unsigned short a_s[2*64*64];
    __shared__ unsigned short b_s[2*128*64];
    const int m0 = blockIdx.x * 64, n0 = blockIdx.y * 128;
    const int tid = threadIdx.x;
    const int wave = tid >> 6, lane = tid & 63;
    const int l15 = lane & 15, l4 = lane >> 4;
    const int nw = wave * 32;
    const int r8 = lane >> 3, c8l = lane & 7;
    const int csw = (c8l ^ r8) * 8;
    const int rp = l15 & 7;
    const f32x4 vzero = {0.f, 0.f, 0.f, 0.f};
    f32x4 acc[4][2];
    #pragma unroll
    for (int i = 0; i < 4; i++){ acc[i][0] = vzero; acc[i][1] = vzero; }

    auto stage = [&](int k0, int buf){
        unsigned short* as = a_s + buf * (64*64);
        unsigned short* bs = b_s + buf * (128*64);
        #pragma unroll
        for (int i = 0; i < 2; i++){               // A: 64 rows = 8 groups
            int rg = wave * 2 + i;
            gl2lds16(wo + (size_t)(m0 + rg*8 + r8) * 512 + k0 + csw, as + rg * 512);
        }
        #pragma unroll
        for (int i = 0; i < 4; i++){               // B: 128 rows = 16 groups
            int rg = wave * 4 + i;
            gl2lds16(attnT + (size_t)(n0 + rg*8 + r8) * 512 + k0 + csw, bs + rg * 512);
        }
    };

    stage(0, 0);
    __syncthreads();

    for (int t = 0; t < 8; t++){
        const int buf = t & 1;
        if (t < 7) stage((t + 1) * 64, buf ^ 1);
        const unsigned short* as = a_s + buf * (64*64);
        const unsigned short* bs = b_s + buf * (128*64);
        #pragma unroll
        for (int kk = 0; kk < 2; kk++){
            bf16x8 af[4], bfr[2];
            #pragma unroll
            for (int mt = 0; mt < 4; mt++)
                af[mt] = *(const bf16x8*)&as[(mt*16 + l15)*64 + (((kk*4) + l4) ^ rp)*8];
            #pragma unroll
            for (int ct = 0; ct < 2; ct++)
                bfr[ct] = *(const bf16x8*)&bs[(nw + ct*16 + l15)*64 + (((kk*4) + l4) ^ rp)*8];
            #pragma unroll
            for (int mt = 0; mt < 4; mt++)
                #pragma unroll
                for (int ct = 0; ct < 2; ct++)
                    acc[mt][ct] = __builtin_amdgcn_mfma_f32_16x16x32_bf16(
                        af[mt], bfr[ct], acc[mt][ct], 0, 0, 0);
        }
        __syncthreads();
    }

    #pragma unroll
    for (int mt = 0; mt < 4; mt++){
        #pragma unroll
        for (int rr = 0; rr < 4; rr++){
            int row = m0 + mt*16 + l4*4 + rr;              // o index
            float bb = bo[row];
            #pragma unroll
            for (int ct2 = 0; ct2 < 2; ct2++){
                int n = n0 + nw + ct2*16 + l15;            // flat b*1024+t
                size_t oaddr = (size_t)(n >> 10) * 524288 + (size_t)row * 1024 + (n & 1023);
                out[oaddr] = acc[mt][ct2][rr] + bb;
            }
        }
    }
}

// ---------------- flash attention: R13-verified (exp2 intrinsic) --------------
// Swapped QK (S^T lane-local), P packed to PV A-fragments fully in-register
// (V rows permuted on the LDS read side), 3-buf K/V pipeline with counted
// vmcnt (never 0 in-loop), __builtin_amdgcn_exp2f for raw v_exp_f32 with
// compiler-visible hazard handling (inline-asm variant FAILED in R12).
__global__ __launch_bounds__(256, 2) void flash_attn(const unsigned short* __restrict__ qt,
                                                     const unsigned short* __restrict__ kt,
                                                     const unsigned short* __restrict__ vct,
                                                     unsigned short* __restrict__ attnT){
    __shared__ unsigned short k_s[3][64*64];
    __shared__ unsigned short v_s[3][64*64];
    const int bhq = blockIdx.x;
    const int bh = bhq & 63, b = bh >> 3, h = bh & 7;
    const int q0 = (bhq >> 6) * 128;
    const int tid = threadIdx.x, wave = tid >> 6, lane = tid & 63;
    const int l15 = lane & 15, l4 = lane >> 4;
    const int r8 = lane >> 3, c8l = lane & 7;
    const int csw = (c8l ^ r8) * 8;
    const int rp = l15 & 7;
    const f32x4 vzero = {0.f, 0.f, 0.f, 0.f};
    const unsigned short* kbase = kt  + (size_t)(b*1024)*512 + h*64;
    const unsigned short* vbase = vct + (size_t)(b*512 + h*64)*1024;

    bf16x8 qf[2][2];
    #pragma unroll
    for (int st = 0; st < 2; st++)
        #pragma unroll
        for (int kh = 0; kh < 2; kh++)
            qf[st][kh] = *(const bf16x8*)(qt + (size_t)(b*1024 + q0 + wave*32 + st*16 + l15)*512
                                             + h*64 + kh*32 + l4*8);
    f32x4 o_acc[2][4], l_acc[2];
    #pragma unroll
    for (int st = 0; st < 2; st++){
        l_acc[st] = vzero;
        #pragma unroll
        for (int dt = 0; dt < 4; dt++) o_acc[st][dt] = vzero;
    }
    const __bf16 one_bf = (__bf16)1.0f;
    const bf16x8 ones = {one_bf, one_bf, one_bf, one_bf, one_bf, one_bf, one_bf, one_bf};

    auto stage = [&](int tile, int buf){
        const int s0n = tile * 64;
        #pragma unroll
        for (int i = 0; i < 2; i++){
            int rg = i * 4 + wave;
            int row = rg * 8 + r8;
            gl2lds16(kbase + (size_t)(s0n + row)*512 + csw, &k_s[buf][rg*512]);
            gl2lds16(vbase + (size_t)row*1024 + s0n + csw, &v_s[buf][rg*512]);
        }
    };
    stage(0, 0);
    stage(1, 1);

    const int voff0 = (l4 & 1) * 4;                // within-chunk half (shorts)
    for (int it = 0; it < 16; ++it){
        const int cur = it % 3;
        // own stage(it) landed; stage(it+1)'s 4 loads stay in flight
        if (it == 15) asm volatile("s_waitcnt vmcnt(0)" ::: "memory");
        else          asm volatile("s_waitcnt vmcnt(4)" ::: "memory");
        __builtin_amdgcn_s_barrier();              // all waves' stage(it) landed
        if (it < 14) stage(it + 2, (it + 2) % 3);  // writes buf[(it-1)%3]: reads done

        bf16x8 kf[2][4];
        #pragma unroll
        for (int kh = 0; kh < 2; kh++)
            #pragma unroll
            for (int ct = 0; ct < 4; ct++)
                kf[kh][ct] = *(const bf16x8*)&k_s[cur][(ct*16 + l15)*64 + ((kh*4 + l4) ^ rp)*8];
        union bfv { bf16x8 v; uint2 u[2]; };
        bfv vfp[2][4];
        #pragma unroll
        for (int c2 = 0; c2 < 2; c2++)
            #pragma unroll
            for (int dt = 0; dt < 4; dt++){
                const int base = (dt*16 + l15)*64;
                const int ch0 = ((c2*4 +     (l4 >> 1)) ^ rp)*8 + voff0;
                const int ch1 = ((c2*4 + 2 + (l4 >> 1)) ^ rp)*8 + voff0;
                vfp[c2][dt].u[0] = *(const uint2*)&v_s[cur][base + ch0];
                vfp[c2][dt].u[1] = *(const uint2*)&v_s[cur][base + ch1];
            }
        #pragma unroll
        for (int st = 0; st < 2; st++){
            f32x4 sa[4];
            #pragma unroll
            for (int ct = 0; ct < 4; ct++) sa[ct] = vzero;
            // swapped operands: S^T -> lane holds S[k=ct*16+l4*4+rr][q=l15]
            #pragma unroll
            for (int kh = 0; kh < 2; kh++)
                #pragma unroll
                for (int ct = 0; ct < 4; ct++)
                    sa[ct] = __builtin_amdgcn_mfma_f32_16x16x32_bf16(kf[kh][ct], qf[st][kh], sa[ct], 0, 0, 0);
            // raw v_exp_f32 via compiler-visible intrinsic (hazards handled)
            #pragma unroll
            for (int ct = 0; ct < 4; ct++)
                #pragma unroll
                for (int rr = 0; rr < 4; rr++)
                    sa[ct][rr] = __builtin_amdgcn_exp2f(sa[ct][rr]);   // q carries log2e/8
            // pack P into A-fragments entirely in-register (trunc, as baseline)
            bf16x8 ap[2];
            #pragma unroll
            for (int c2 = 0; c2 < 2; c2++){
                union { unsigned u[4]; bf16x8 v; } pw;
                #pragma unroll
                for (int c1 = 0; c1 < 2; c1++){
                    union { float f; unsigned u; } x0, x1, x2, x3;
                    x0.f = sa[2*c2+c1][0]; x1.f = sa[2*c2+c1][1];
                    x2.f = sa[2*c2+c1][2]; x3.f = sa[2*c2+c1][3];
                    pw.u[c1*2+0] = (x0.u >> 16) | (x1.u & 0xffff0000u);
                    pw.u[c1*2+1] = (x2.u >> 16) | (x3.u & 0xffff0000u);
                }
                ap[c2] = pw.v;
            }
            l_acc[st] = __builtin_amdgcn_mfma_f32_16x16x32_bf16(ap[0], ones, l_acc[st], 0, 0, 0);
            l_acc[st] = __builtin_amdgcn_mfma_f32_16x16x32_bf16(ap[1], ones, l_acc[st], 0, 0, 0);
            #pragma unroll
            for (int dt = 0; dt < 4; dt++){
                o_acc[st][dt] = __builtin_amdgcn_mfma_f32_16x16x32_bf16(ap[0], vfp[0][dt].v, o_acc[st][dt], 0, 0, 0);
                o_acc[st][dt] = __builtin_amdgcn_mfma_f32_16x16x32_bf16(ap[1], vfp[1][dt].v, o_acc[st][dt], 0, 0, 0);
            }
        }
    }
    #pragma unroll
    for (int st = 0; st < 2; st++){
        float rl[4];
        #pragma unroll
        for (int rr = 0; rr < 4; rr++) rl[rr] = __builtin_amdgcn_rcpf(l_acc[st][rr]);
        #pragma unroll
        for (int dt = 0; dt < 4; dt++)
            #pragma unroll
            for (int rr = 0; rr < 4; rr++){
                int row = q0 + wave*32 + st*16 + l4*4 + rr;
                attnT[(size_t)(b*1024 + row)*512 + h*64 + dt*16 + l15] = f2bf(o_acc[st][dt][rr] * rl[rr]);
            }
    }
}

extern "C" void kernel_launch(void* const* d_in, const int* in_sizes, int n_in,
                              void* d_out, int out_size, void* d_ws, size_t ws_size,
                              hipStream_t stream){
    const float* x  = (const float*)d_in[0];
    const float* c  = (const float*)d_in[1];
    const float* Wq = (const float*)d_in[2];
    const float* bq = (const float*)d_in[3];
    const float* Wk = (const float*)d_in[4];
    const float* bk = (const float*)d_in[5];
    const float* Wv = (const float*)d_in[6];
    const float* bv = (const float*)d_in[7];
    const float* Wo = (const float*)d_in[8];
    const float* bo = (const float*)d_in[9];

    unsigned short* wq_b = (unsigned short*)d_ws;
    unsigned short* wk_b = wq_b + 262144;
    unsigned short* wv_b = wk_b + 262144;
    unsigned short* wo_b = wv_b + 262144;
    unsigned short* xt   = wo_b + 262144;
    unsigned short* ct   = xt  + 4194304;
    unsigned short* qt   = ct  + 4194304;
    unsigned short* kt   = qt  + 4194304;
    unsigned short* vct  = kt  + 4194304;
    unsigned short* attnT = xt;                            // xt dead after q-GEMM

    transpose_cvt<<<dim3(16, 8, 17), 256, 0, stream>>>(x, c, Wq, Wk, Wv, Wo,
                                                       xt, ct, wq_b, wk_b, wv_b, wo_b);
    qkv_gemm<<<dim3(256, 3), 256, 0, stream>>>(xt, ct, wq_b, wk_b, wv_b, bq, bk, bv, qt, kt, vct);
    flash_attn<<<dim3(512), 256, 0, stream>>>(qt, kt, vct, attnT);
    gemm_o<<<dim3(8, 64), 256, 0, stream>>>(wo_b, attnT, bo, (float*)d_out);
}